// Round 1
// baseline (280.829 us; speedup 1.0000x reference)
//
#include <hip/hip_runtime.h>
#include <hip/hip_bf16.h>

// ObjWise: out = mask ? relu(input @ W + b) : 0
// input (131072 x 256) f32, W (256 x 256) f32, b (256) f32, out (131072 x 256) f32.
// Memory-bound: ~201-268 MB HBM traffic -> ~32-43 us floor at 6.3 TB/s.
// Strategy: bf16 MFMA (16x16x32) GEMM, no LDS; W pre-converted to B-fragment
// layout in d_ws (L2-resident); masked rows skip the A-fetch entirely.

typedef __attribute__((ext_vector_type(8))) short bf16x8;   // 8 bf16 = 4 VGPR
typedef __attribute__((ext_vector_type(4))) float f32x4;    // 4 f32  = 4 VGPR

#define KD 256
#define ND 256

static __device__ __forceinline__ unsigned short f2bf(float f) {
  // round-to-nearest-even f32 -> bf16 bits (inputs are finite; no NaN handling)
  union { float f; unsigned u; } x; x.f = f;
  unsigned r = x.u + 0x7FFFu + ((x.u >> 16) & 1u);
  return (unsigned short)(r >> 16);
}

// ---- mask dtype detection -------------------------------------------------
// The harness may store the bool mask as raw bytes (1B), int32, or f32.
// Scan first 256 words (1 KB; smallest possible buffer is 128 KB):
//   any word == 0x3F800000 -> f32 (flag 2)
//   any word > 1           -> packed bytes (flag 1)
//   else                   -> int32 0/1 (flag 0)
__global__ void detect_mask_kernel(const unsigned int* __restrict__ mw,
                                   int* __restrict__ flag) {
  __shared__ int s;
  if (threadIdx.x == 0) s = 0;
  __syncthreads();
  unsigned w = mw[threadIdx.x];
  int f = 0;
  if (w == 0x3F800000u) f = 2;
  else if (w > 1u) f = 1;
  if (f) atomicOr(&s, f);
  __syncthreads();
  if (threadIdx.x == 0) *flag = (s & 2) ? 2 : (s & 1);
}

static __device__ __forceinline__ bool mrow(const void* mp, int flag, int row) {
  if (flag == 2) return ((const float*)mp)[row] != 0.0f;
  if (flag == 1) return ((const unsigned char*)mp)[row] != 0;
  return ((const int*)mp)[row] != 0;
}

// ---- W -> bf16 B-fragment layout ------------------------------------------
// mfma_f32_16x16x32_bf16 B operand (32x16): lane = (n&15) + 16*((k&31)>>3),
// elem = k&7. Stored as wf[((n_blk*8 + k_blk)*64 + lane)*8 + elem].
__global__ void prep_w_kernel(const float* __restrict__ W,
                              unsigned short* __restrict__ wf) {
  int k = blockIdx.x;    // 0..255 (D_in)
  int n = threadIdx.x;   // 0..255 (D_out)
  float v = W[k * ND + n];
  int nb = n >> 4;
  int kb = k >> 5;
  int lane = (n & 15) | (((k >> 3) & 3) << 4);
  int e = k & 7;
  wf[(((nb << 3) | kb) << 9) + (lane << 3) + e] = f2bf(v);
}

// ---- main GEMM ------------------------------------------------------------
// Block = 256 threads = 4 waves; block tile 64 rows x 256 cols.
// Wave (w>>1) picks 32-row half, (w&1) picks 128-col half.
// Per wave: acc[2 row-frags][8 n-frags] of f32x4; K-loop of 8 x BK=32.
__global__ __launch_bounds__(256) void objwise_gemm(
    const float* __restrict__ A, const void* __restrict__ mask,
    const unsigned short* __restrict__ wf, const float* __restrict__ bias,
    float* __restrict__ out, const int* __restrict__ flagp) {
  const int flag = *flagp;
  const int tid  = threadIdx.x;
  const int wave = tid >> 6;
  const int lane = tid & 63;
  const int rb = blockIdx.x * 64 + (wave >> 1) * 32;  // wave row base
  const int cb = (wave & 1) * 128;                    // wave col base

  // A-fragment addressing: row = rb + (lane&15) [+16], k = kb*32 + (lane>>4)*8
  const int r0   = rb + (lane & 15);
  const int r1   = r0 + 16;
  const int koff = (lane >> 4) << 3;

  const bool m0 = mrow(mask, flag, r0);
  const bool m1 = mrow(mask, flag, r1);

  const float* a0p = A + (size_t)r0 * KD + koff;
  const float* a1p = A + (size_t)r1 * KD + koff;
  // B fragments: element index = (nb<<12) + (kb<<9) + lane*8
  const unsigned short* wfl = wf + ((size_t)(cb >> 4) << 12) + (lane << 3);

  f32x4 acc[2][8];
#pragma unroll
  for (int i = 0; i < 8; ++i) {
    acc[0][i] = (f32x4){0.f, 0.f, 0.f, 0.f};
    acc[1][i] = (f32x4){0.f, 0.f, 0.f, 0.f};
  }

#pragma unroll 2
  for (int kb = 0; kb < 8; ++kb) {
    bf16x8 a0 = (bf16x8){0,0,0,0,0,0,0,0};
    bf16x8 a1 = (bf16x8){0,0,0,0,0,0,0,0};
    if (m0) {  // masked rows: skip the fetch entirely (saves HBM lines)
      f32x4 x = *(const f32x4*)(a0p + kb * 32);
      f32x4 y = *(const f32x4*)(a0p + kb * 32 + 4);
      a0[0] = (short)f2bf(x[0]); a0[1] = (short)f2bf(x[1]);
      a0[2] = (short)f2bf(x[2]); a0[3] = (short)f2bf(x[3]);
      a0[4] = (short)f2bf(y[0]); a0[5] = (short)f2bf(y[1]);
      a0[6] = (short)f2bf(y[2]); a0[7] = (short)f2bf(y[3]);
    }
    if (m1) {
      f32x4 x = *(const f32x4*)(a1p + kb * 32);
      f32x4 y = *(const f32x4*)(a1p + kb * 32 + 4);
      a1[0] = (short)f2bf(x[0]); a1[1] = (short)f2bf(x[1]);
      a1[2] = (short)f2bf(x[2]); a1[3] = (short)f2bf(x[3]);
      a1[4] = (short)f2bf(y[0]); a1[5] = (short)f2bf(y[1]);
      a1[6] = (short)f2bf(y[2]); a1[7] = (short)f2bf(y[3]);
    }
#pragma unroll
    for (int n = 0; n < 8; ++n) {
      bf16x8 bfr = *(const bf16x8*)(wfl + ((size_t)n << 12) + (kb << 9));
      acc[0][n] = __builtin_amdgcn_mfma_f32_16x16x32_bf16(a0, bfr, acc[0][n], 0, 0, 0);
      acc[1][n] = __builtin_amdgcn_mfma_f32_16x16x32_bf16(a1, bfr, acc[1][n], 0, 0, 0);
    }
  }

  // Epilogue. C/D layout (m89-verified): col = lane&15, row = (lane>>4)*4 + reg.
  const int col0 = cb + (lane & 15);
  const int rr   = rb + ((lane >> 4) << 2);  // global row for reg j = rr + j

  bool mm0[4], mm1[4];
#pragma unroll
  for (int j = 0; j < 4; ++j) {
    mm0[j] = mrow(mask, flag, rr + j);
    mm1[j] = mrow(mask, flag, rr + 16 + j);
  }
  float bvs[8];
#pragma unroll
  for (int n = 0; n < 8; ++n) bvs[n] = bias[col0 + (n << 4)];

#pragma unroll
  for (int n = 0; n < 8; ++n) {
    const int col = col0 + (n << 4);
#pragma unroll
    for (int j = 0; j < 4; ++j) {
      float v0 = fmaxf(acc[0][n][j] + bvs[n], 0.f);
      out[(size_t)(rr + j) * ND + col] = mm0[j] ? v0 : 0.f;
      float v1 = fmaxf(acc[1][n][j] + bvs[n], 0.f);
      out[(size_t)(rr + 16 + j) * ND + col] = mm1[j] ? v1 : 0.f;
    }
  }
}

extern "C" void kernel_launch(void* const* d_in, const int* in_sizes, int n_in,
                              void* d_out, int out_size, void* d_ws, size_t ws_size,
                              hipStream_t stream) {
  const float* A    = (const float*)d_in[0];
  const void*  mask = d_in[1];
  const float* W    = (const float*)d_in[2];
  const float* bias = (const float*)d_in[3];
  float* out = (float*)d_out;

  int* flag = (int*)d_ws;                                    // 4 B
  unsigned short* wf = (unsigned short*)((char*)d_ws + 256); // 128 KiB fragments

  detect_mask_kernel<<<1, 256, 0, stream>>>((const unsigned int*)mask, flag);
  prep_w_kernel<<<256, 256, 0, stream>>>(W, wf);
  // M = 131072 rows / 64 rows per block = 2048 blocks
  objwise_gemm<<<2048, 256, 0, stream>>>(A, mask, wf, bias, out, flag);
}

// Round 5
// 258.633 us; speedup vs baseline: 1.0858x; 1.0858x over previous
//
#include <hip/hip_runtime.h>
#include <hip/hip_bf16.h>

// ObjWise: out = mask ? relu(input @ W + b) : 0
// input (131072 x 256) f32, W (256 x 256) f32, b (256) f32, out f32.
// R1 post-mortem: scattered per-lane A loads (64 lines/instr) made the kernel
// TA/latency-bound (MfmaUtil 5.8%, VALU 12%, occ 27%, 108 us).
// R2: coalesced staging of A (contiguous 64KB/block) -> bf16 XOR-swizzled LDS,
// ds_read_b128 fragments (2-way alias = free), 64x64 wave tile (B L2 traffic /2).
// (resubmitted unchanged after R2/R3/R4 bench infra timeouts)

typedef __attribute__((ext_vector_type(8))) short bf16x8;   // 8 bf16 = 4 VGPR
typedef __attribute__((ext_vector_type(4))) float f32x4;    // 4 f32
typedef __attribute__((ext_vector_type(2))) unsigned int u32x2;

#define KD 256
#define ND 256
#define BM 64

static __device__ __forceinline__ unsigned short f2bf(float f) {
  // round-to-nearest-even f32 -> bf16 bits
  union { float f; unsigned u; } x; x.f = f;
  unsigned r = x.u + 0x7FFFu + ((x.u >> 16) & 1u);
  return (unsigned short)(r >> 16);
}

static __device__ __forceinline__ bool mrow(const void* mp, int flag, size_t row) {
  if (flag == 2) return ((const float*)mp)[row] != 0.0f;
  if (flag == 1) return ((const unsigned char*)mp)[row] != 0;
  return ((const int*)mp)[row] != 0;
}

// ---- W -> bf16 B-fragment layout, + mask dtype detection (block 0) ---------
// B frag (16x16x32): lane = (n&15) + 16*((k&31)>>3), elem = k&7.
// Stored wf[((nb*8 + kb)*64 + lane)*8 + elem].  (verified passing in R1)
__global__ void prep_w_kernel(const float* __restrict__ W,
                              unsigned short* __restrict__ wf,
                              const unsigned int* __restrict__ mw,
                              int* __restrict__ flag) {
  int k = blockIdx.x;    // 0..255 (D_in)
  int n = threadIdx.x;   // 0..255 (D_out)
  float v = W[k * ND + n];
  int nb = n >> 4;
  int kb = k >> 5;
  int lane = (n & 15) | (((k >> 3) & 3) << 4);
  int e = k & 7;
  wf[(((nb << 3) | kb) << 9) + (lane << 3) + e] = f2bf(v);

  if (blockIdx.x == 0) {
    // mask dtype: f32 (flag 2) / packed bytes (flag 1) / int32 0-1 (flag 0)
    __shared__ int s;
    if (threadIdx.x == 0) s = 0;
    __syncthreads();
    unsigned w = mw[threadIdx.x];
    int f = 0;
    if (w == 0x3F800000u) f = 2;
    else if (w > 1u) f = 1;
    if (f) atomicOr(&s, f);
    __syncthreads();
    if (threadIdx.x == 0) *flag = (s & 2) ? 2 : (s & 1);
  }
}

// ---- main GEMM ------------------------------------------------------------
// Block = 256 threads = 4 waves; block tile 64 rows x 256 cols (full N).
// Wave w owns 64 rows x 64 cols (cols w*64..). acc[4 row-frags][4 n-frags].
// A staged in LDS as bf16, XOR-swizzled: byte ^= (row&7)<<4.
__global__ __launch_bounds__(256, 4) void objwise_gemm(
    const float* __restrict__ A, const void* __restrict__ mask,
    const unsigned short* __restrict__ wf, const float* __restrict__ bias,
    float* __restrict__ out, const int* __restrict__ flagp) {
  __shared__ __align__(16) unsigned char As[BM * KD * 2];  // 32 KiB

  const int flag = *flagp;
  const int tid  = threadIdx.x;
  const int wave = tid >> 6;
  const int lane = tid & 63;
  const size_t rowbase = (size_t)blockIdx.x * BM;

  // ---- stage A: contiguous 64 KB -> bf16 swizzled LDS ----------------------
  // iter i: thread t handles 16B at float index i*1024 + t*4 (fully coalesced:
  // one instruction covers 1KB contiguous). row = i*4 + t/64, col = (t*4)&255.
  const float* Ab = A + rowbase * KD;
#pragma unroll
  for (int i = 0; i < 16; ++i) {
    f32x4 v = *(const f32x4*)(Ab + i * 1024 + tid * 4);
    int row  = (i << 2) + (tid >> 6);
    int colb = (tid << 3) & 511;                         // byte col within row
    int baddr = ((row << 9) | colb) ^ ((row & 7) << 4);  // swizzled
    unsigned p0 = (unsigned)f2bf(v[0]) | ((unsigned)f2bf(v[1]) << 16);
    unsigned p1 = (unsigned)f2bf(v[2]) | ((unsigned)f2bf(v[3]) << 16);
    *(u32x2*)(As + baddr) = (u32x2){p0, p1};
  }
  __syncthreads();

  // ---- compute -------------------------------------------------------------
  const int cb = wave << 6;                              // wave col base
  const unsigned short* wfl = wf + ((size_t)(cb >> 4) << 12) + (lane << 3);

  f32x4 acc[4][4];
#pragma unroll
  for (int fr = 0; fr < 4; ++fr)
#pragma unroll
    for (int nb = 0; nb < 4; ++nb)
      acc[fr][nb] = (f32x4){0.f, 0.f, 0.f, 0.f};

  const int arow_l = lane & 15;          // A-frag row within 16-row frag
  const int gbyte  = (lane >> 4) << 4;   // 16B k-group offset

#pragma unroll 2
  for (int kb = 0; kb < 8; ++kb) {
    bf16x8 af[4];
#pragma unroll
    for (int fr = 0; fr < 4; ++fr) {
      int row  = (fr << 4) + arow_l;
      int addr = (((row << 9) | ((kb << 6) + gbyte))) ^ ((row & 7) << 4);
      af[fr] = *(const bf16x8*)(As + addr);
    }
#pragma unroll
    for (int nb = 0; nb < 4; ++nb) {
      bf16x8 bfr = *(const bf16x8*)(wfl + ((size_t)nb << 12) + (kb << 9));
      acc[0][nb] = __builtin_amdgcn_mfma_f32_16x16x32_bf16(af[0], bfr, acc[0][nb], 0, 0, 0);
      acc[1][nb] = __builtin_amdgcn_mfma_f32_16x16x32_bf16(af[1], bfr, acc[1][nb], 0, 0, 0);
      acc[2][nb] = __builtin_amdgcn_mfma_f32_16x16x32_bf16(af[2], bfr, acc[2][nb], 0, 0, 0);
      acc[3][nb] = __builtin_amdgcn_mfma_f32_16x16x32_bf16(af[3], bfr, acc[3][nb], 0, 0, 0);
    }
  }

  // ---- epilogue: +bias, relu, mask-zero, store ----------------------------
  // C/D layout: col = lane&15, row = (lane>>4)*4 + reg.
  const int col0 = cb + (lane & 15);
  float bvs[4];
#pragma unroll
  for (int nb = 0; nb < 4; ++nb) bvs[nb] = bias[col0 + (nb << 4)];

#pragma unroll
  for (int fr = 0; fr < 4; ++fr) {
    const int rl = (fr << 4) + ((lane >> 4) << 2);
#pragma unroll
    for (int j = 0; j < 4; ++j) {
      const size_t grow = rowbase + rl + j;
      const bool mm = mrow(mask, flag, grow);
      float* op = out + grow * ND + col0;
#pragma unroll
      for (int nb = 0; nb < 4; ++nb) {
        float v = fmaxf(acc[fr][nb][j] + bvs[nb], 0.f);
        op[nb << 4] = mm ? v : 0.f;
      }
    }
  }
}

extern "C" void kernel_launch(void* const* d_in, const int* in_sizes, int n_in,
                              void* d_out, int out_size, void* d_ws, size_t ws_size,
                              hipStream_t stream) {
  const float* A    = (const float*)d_in[0];
  const void*  mask = d_in[1];
  const float* W    = (const float*)d_in[2];
  const float* bias = (const float*)d_in[3];
  float* out = (float*)d_out;

  int* flag = (int*)d_ws;                                    // 4 B
  unsigned short* wf = (unsigned short*)((char*)d_ws + 256); // 128 KiB fragments

  prep_w_kernel<<<256, 256, 0, stream>>>(W, wf, (const unsigned int*)mask, flag);
  // 131072 rows / 64 per block = 2048 blocks
  objwise_gemm<<<2048, 256, 0, stream>>>(A, mask, wf, bias, out, flag);
}

// Round 6
// 255.009 us; speedup vs baseline: 1.1013x; 1.0142x over previous
//
#include <hip/hip_runtime.h>
#include <hip/hip_bf16.h>

// ObjWise: out = mask ? relu(input @ W + b) : 0
// input (131072 x 256) f32, W (256 x 256) f32, b (256) f32, out f32.
// R1: scattered A loads -> TA-bound, 108 us. R2: coalesced LDS staging, 96 us
// but STILL latency-bound (Mfma 6.7%, VALU 10.7%, hbm 2.05 TB/s, occ 34%):
// stage->barrier->compute->store phases never overlap within a block.
// R3: persistent blocks, 4 tiles each, LDS double-buffer, T14 issue-early
// prefetch (next tile's HBM loads in flight under current tile's MFMA loop),
// one barrier per tile, mask row-skip via per-tile __ballot.

typedef __attribute__((ext_vector_type(8))) short bf16x8;   // 8 bf16 = 4 VGPR
typedef __attribute__((ext_vector_type(4))) float f32x4;    // 4 f32
typedef __attribute__((ext_vector_type(2))) unsigned int u32x2;

#define KD 256
#define ND 256
#define BM 64
#define TILES 4
#define GRID 512   // 512 blocks * 4 tiles * 64 rows = 131072

static __device__ __forceinline__ unsigned short f2bf(float f) {
  // round-to-nearest-even f32 -> bf16 bits
  union { float f; unsigned u; } x; x.f = f;
  unsigned r = x.u + 0x7FFFu + ((x.u >> 16) & 1u);
  return (unsigned short)(r >> 16);
}

static __device__ __forceinline__ bool mrow(const void* mp, int flag, size_t row) {
  if (flag == 2) return ((const float*)mp)[row] != 0.0f;
  if (flag == 1) return ((const unsigned char*)mp)[row] != 0;
  return ((const int*)mp)[row] != 0;
}

// ---- W -> bf16 B-fragment layout, + mask dtype detection (block 0) ---------
// B frag (16x16x32): lane = (n&15) + 16*((k&31)>>3), elem = k&7.
// Stored wf[((nb*8 + kb)*64 + lane)*8 + elem].  (verified R1/R2)
__global__ void prep_w_kernel(const float* __restrict__ W,
                              unsigned short* __restrict__ wf,
                              const unsigned int* __restrict__ mw,
                              int* __restrict__ flag) {
  int k = blockIdx.x;    // 0..255 (D_in)
  int n = threadIdx.x;   // 0..255 (D_out)
  float v = W[k * ND + n];
  int nb = n >> 4;
  int kb = k >> 5;
  int lane = (n & 15) | (((k >> 3) & 3) << 4);
  int e = k & 7;
  wf[(((nb << 3) | kb) << 9) + (lane << 3) + e] = f2bf(v);

  if (blockIdx.x == 0) {
    // mask dtype: f32 (flag 2) / packed bytes (flag 1) / int32 0-1 (flag 0)
    __shared__ int s;
    if (threadIdx.x == 0) s = 0;
    __syncthreads();
    unsigned w = mw[threadIdx.x];
    int f = 0;
    if (w == 0x3F800000u) f = 2;
    else if (w > 1u) f = 1;
    if (f) atomicOr(&s, f);
    __syncthreads();
    if (threadIdx.x == 0) *flag = (s & 2) ? 2 : (s & 1);
  }
}

// ---- main GEMM ------------------------------------------------------------
// 512 persistent blocks x 4 waves; each block: 4 tiles of 64 rows x 256 cols.
// Wave w owns 64 rows x 64 cols. LDS: 2 x 32KB bf16 double-buffer, XOR-swizzled
// byte ^= (row&7)<<4. Pipeline per tile: pack(pre)->LDS[t&1]; barrier;
// prefetch(t+1)->pre (in flight under compute); compute; masked stores.
__global__ __launch_bounds__(256, 2) void objwise_gemm(
    const float* __restrict__ A, const void* __restrict__ mask,
    const unsigned short* __restrict__ wf, const float* __restrict__ bias,
    float* __restrict__ out, const int* __restrict__ flagp) {
  __shared__ __align__(16) unsigned char As[2][BM * KD * 2];  // 2 x 32 KiB

  const int flag = *flagp;
  const int tid  = threadIdx.x;
  const int wave = tid >> 6;
  const int lane = tid & 63;
  const int tile0 = blockIdx.x * TILES;

  // per-thread staging map (same as R2): iter i covers floats [i*1024 + tid*4]
  // -> row = i*4 + tid/64 (wave-uniform!), byte col = (tid*8)&511
  const int srowL = tid >> 6;             // + i*4
  const int colb  = (tid << 3) & 511;

  // B fragment base: wave covers cols wave*64.. ; elem idx = nb<<12 | kb<<9 | lane*8
  const int cb = wave << 6;
  const unsigned short* wfl = wf + ((size_t)(cb >> 4) << 12) + (lane << 3);

  const int arow_l = lane & 15;
  const int gbyte  = (lane >> 4) << 4;
  const int col0   = cb + (lane & 15);
  float bvs[4];
#pragma unroll
  for (int nb = 0; nb < 4; ++nb) bvs[nb] = bias[col0 + (nb << 4)];

  // ---- prefetch tile 0 ----
  f32x4 pre[16];
#pragma unroll
  for (int i = 0; i < 16; ++i) pre[i] = (f32x4){0.f, 0.f, 0.f, 0.f};

  unsigned long long bm = __ballot(mrow(mask, flag, (size_t)tile0 * BM + lane));
  {
    const float* Ab = A + (size_t)tile0 * BM * KD;
#pragma unroll
    for (int i = 0; i < 16; ++i) {
      int rowL = (i << 2) + srowL;                  // wave-uniform predicate
      if ((bm >> rowL) & 1ULL) pre[i] = *(const f32x4*)(Ab + i * 1024 + tid * 4);
    }
  }

  for (int t = 0; t < TILES; ++t) {
    const size_t rowbase = (size_t)(tile0 + t) * BM;
    unsigned char* Al = As[t & 1];

    // ---- pack pre -> LDS[t&1] (vmcnt waits inserted by compiler) ----------
#pragma unroll
    for (int i = 0; i < 16; ++i) {
      int row   = (i << 2) + srowL;
      int baddr = ((row << 9) | colb) ^ ((row & 7) << 4);
      unsigned p0 = (unsigned)f2bf(pre[i][0]) | ((unsigned)f2bf(pre[i][1]) << 16);
      unsigned p1 = (unsigned)f2bf(pre[i][2]) | ((unsigned)f2bf(pre[i][3]) << 16);
      *(u32x2*)(Al + baddr) = (u32x2){p0, p1};
    }
    __syncthreads();   // LDS[t&1] ready; also fences reuse of LDS[(t+1)&1]

    // ---- issue next tile's loads EARLY (hide HBM under this tile's MFMA) --
    unsigned long long bm_next = 0;
    if (t + 1 < TILES) {
      bm_next = __ballot(mrow(mask, flag, rowbase + BM + lane));
      const float* Ab = A + (rowbase + BM) * KD;
#pragma unroll
      for (int i = 0; i < 16; ++i) {
        int rowL = (i << 2) + srowL;
        if ((bm_next >> rowL) & 1ULL) pre[i] = *(const f32x4*)(Ab + i * 1024 + tid * 4);
      }
    }

    // ---- compute ----------------------------------------------------------
    f32x4 acc[4][4];
#pragma unroll
    for (int fr = 0; fr < 4; ++fr)
#pragma unroll
      for (int nb = 0; nb < 4; ++nb)
        acc[fr][nb] = (f32x4){0.f, 0.f, 0.f, 0.f};

#pragma unroll 2
    for (int kb = 0; kb < 8; ++kb) {
      bf16x8 af[4];
#pragma unroll
      for (int fr = 0; fr < 4; ++fr) {
        int row  = (fr << 4) + arow_l;
        int addr = (((row << 9) | ((kb << 6) + gbyte))) ^ ((row & 7) << 4);
        af[fr] = *(const bf16x8*)(Al + addr);
      }
#pragma unroll
      for (int nb = 0; nb < 4; ++nb) {
        bf16x8 bfr = *(const bf16x8*)(wfl + ((size_t)nb << 12) + (kb << 9));
        acc[0][nb] = __builtin_amdgcn_mfma_f32_16x16x32_bf16(af[0], bfr, acc[0][nb], 0, 0, 0);
        acc[1][nb] = __builtin_amdgcn_mfma_f32_16x16x32_bf16(af[1], bfr, acc[1][nb], 0, 0, 0);
        acc[2][nb] = __builtin_amdgcn_mfma_f32_16x16x32_bf16(af[2], bfr, acc[2][nb], 0, 0, 0);
        acc[3][nb] = __builtin_amdgcn_mfma_f32_16x16x32_bf16(af[3], bfr, acc[3][nb], 0, 0, 0);
      }
    }

    // ---- epilogue: +bias, relu, mask-zero (bits from bm), store -----------
    // C/D layout: col = lane&15, row = (lane>>4)*4 + reg.
#pragma unroll
    for (int fr = 0; fr < 4; ++fr) {
      const int rl = (fr << 4) + ((lane >> 4) << 2);
#pragma unroll
      for (int j = 0; j < 4; ++j) {
        const bool mm = (bm >> (rl + j)) & 1ULL;
        float* op = out + (rowbase + rl + j) * ND + col0;
#pragma unroll
        for (int nb = 0; nb < 4; ++nb) {
          float v = fmaxf(acc[fr][nb][j] + bvs[nb], 0.f);
          op[nb << 4] = mm ? v : 0.f;
        }
      }
    }
    bm = bm_next;
  }
}

extern "C" void kernel_launch(void* const* d_in, const int* in_sizes, int n_in,
                              void* d_out, int out_size, void* d_ws, size_t ws_size,
                              hipStream_t stream) {
  const float* A    = (const float*)d_in[0];
  const void*  mask = d_in[1];
  const float* W    = (const float*)d_in[2];
  const float* bias = (const float*)d_in[3];
  float* out = (float*)d_out;

  int* flag = (int*)d_ws;                                    // 4 B
  unsigned short* wf = (unsigned short*)((char*)d_ws + 256); // 128 KiB fragments

  prep_w_kernel<<<256, 256, 0, stream>>>(W, wf, (const unsigned int*)mask, flag);
  objwise_gemm<<<GRID, 256, 0, stream>>>(A, mask, wf, bias, out, flag);
}